// Round 2
// 274.210 us; speedup vs baseline: 1.0933x; 1.0933x over previous
//
#include <hip/hip_runtime.h>
#include <stdint.h>

// BinarizeConv2dSDP: out = conv3x3(sign(x), sign(M), pad=1) * Alpha[o]
// R6 (retry; prior round was an infra container failure, no signal):
//     GEMM switched from non-scaled fp8 32x32x16 MFMA (bf16 rate) to
//     MX-scaled 32x32x64 f8f6f4 MFMA with unit scales (0x7F e8m0 = 1.0):
//     2x MFMA rate, 4x K per instruction, identical operand bytes/addresses
//     (k-permutation applied consistently to A and B => same dot product).
//     binarize_act / pack_w unchanged from R5 (verified absmax 0.0).

typedef __attribute__((ext_vector_type(16))) float floatx16;
typedef __attribute__((ext_vector_type(8)))  int   intx8;

#define N_IMG 32
#define C_IN  256
#define O_OUT 256
#define HP 58
#define WP 58
#define GPI 3136                                    // 56*56 px per image
#define APAD_POS ((size_t)N_IMG * HP * WP)          // 107648 padded positions
#define APAD_BYTES (APAD_POS * C_IN)                // 27.6 MB fp8
#define TPI 13
#define AL_GRAN 1072
#define WL_GRAN 1536

__device__ __forceinline__ unsigned int sgn8(float x) {
    // fp8 e4m3fn: +1.0 = 0x38, -1.0 = 0xB8, 0 = 0x00
    return x > 0.f ? 0x38u : (x < 0.f ? 0xB8u : 0u);
}

__device__ __forceinline__ void glds16(const unsigned char* g, unsigned char* l) {
    __builtin_amdgcn_global_load_lds(
        (const __attribute__((address_space(1))) unsigned int*)g,
        (__attribute__((address_space(3))) unsigned int*)l, 16, 0, 0);
}

// ---------------------------------------------------------------------------
// Binarize x (NCHW fp32) -> zero-padded NHWC fp8 sign buffer.
// Block = one (n, hp) padded row, ALL 256 channels.
// Phase 1: float4 loads -> tile[ci][word] (u32 = 4 w-packed sign bytes).
// Phase 2a: repack w-packed -> channel-packed u32 in LDS2[w][cq]
//   (reads: 4-lane same-addr broadcast x 16 addrs over 8 banks = 2-way, free).
// Phase 2b: uint4 reads from LDS2 -> 1 KB contiguous store per wave.
__global__ __launch_bounds__(256) void binarize_act(
    const float* __restrict__ x, unsigned char* __restrict__ apad)
{
    int bid = blockIdx.x;
    int n = bid / HP;
    int hp = bid - n * HP;
    int tid = threadIdx.x;

    unsigned char* rowp = apad + ((size_t)(n * HP + hp) * WP) * C_IN;
    uint4 z = {0u, 0u, 0u, 0u};

    if (hp == 0 || hp == HP - 1) {                    // border rows: zero 58x256B
#pragma unroll
        for (int j = 0; j < 4; ++j) {
            int t = tid + 256 * j;                    // < 928 = 58*16
            if (t < WP * 16) {
                int w = t >> 4, g = t & 15;
                *(uint4*)(rowp + (size_t)w * C_IN + g * 16) = z;
            }
        }
        return;
    }
    int h = hp - 1;

    __shared__ unsigned int tile[C_IN * 15];          // [ci][word0..13], stride 15
    __shared__ unsigned int lds2[56 * 65];            // [w][cq0..63], stride 65

    const float* xb = x + ((size_t)n * C_IN) * GPI + h * 56;
#pragma unroll
    for (int j = 0; j < 14; ++j) {                    // 256 ch x 14 float4
        int t = tid + 256 * j;
        int ci = t / 14;
        int w4 = t - ci * 14;
        float4 v = *(const float4*)(xb + (size_t)ci * GPI + w4 * 4);
        tile[ci * 15 + w4] = sgn8(v.x) | (sgn8(v.y) << 8) |
                             (sgn8(v.z) << 16) | (sgn8(v.w) << 24);
    }
    __syncthreads();

    // Phase 2a: t = whi*256 + cq*4 + wlo ; w = whi*4+wlo ; cq = channel quad
#pragma unroll
    for (int j = 0; j < 14; ++j) {
        int t = tid + 256 * j;                        // < 3584 = 14*64*4
        int wlo = t & 3;
        int cq  = (t >> 2) & 63;
        int whi = t >> 8;
        int sh = wlo * 8;
        unsigned int r = 0;
#pragma unroll
        for (int i = 0; i < 4; ++i) {
            unsigned int v = tile[(cq * 4 + i) * 15 + whi];
            r |= ((v >> sh) & 0xFFu) << (8 * i);
        }
        lds2[(whi * 4 + wlo) * 65 + cq] = r;
    }
    __syncthreads();

    // Phase 2b: 56 w x 16 uint4 -> contiguous stores (pos w+1, c = g*16..)
#pragma unroll
    for (int j = 0; j < 4; ++j) {
        int t = tid + 256 * j;                        // < 896 = 56*16
        if (t < 896) {
            int w = t >> 4, g = t & 15;
            uint4 v;
            v.x = lds2[w * 65 + g * 4 + 0];
            v.y = lds2[w * 65 + g * 4 + 1];
            v.z = lds2[w * 65 + g * 4 + 2];
            v.w = lds2[w * 65 + g * 4 + 3];
            *(uint4*)(rowp + (size_t)(w + 1) * C_IN + g * 16) = v;
        }
    }
    if (tid < 32) {                                   // zero pad cols 0 and 57
        int g = tid & 15;
        int col = (tid >> 4) * (WP - 1);
        *(uint4*)(rowp + (size_t)col * C_IN + g * 16) = z;
    }
}

// ---------------------------------------------------------------------------
// M (O,C,3,3) fp32 -> wpk[t][o][c] fp8 sign, t = kh*3+kw. Thread = (o, c4).
__global__ __launch_bounds__(256) void pack_w(
    const float* __restrict__ M, unsigned char* __restrict__ wpk)
{
    int gid = blockIdx.x * 256 + threadIdx.x;         // 16384
    int o = gid >> 6;
    int c4 = (gid & 63) << 2;
    const float* mb = M + (size_t)(o * C_IN + c4) * 9;
#pragma unroll
    for (int t = 0; t < 9; ++t) {
        unsigned int r = sgn8(mb[t]) | (sgn8(mb[9 + t]) << 8) |
                         (sgn8(mb[18 + t]) << 16) | (sgn8(mb[27 + t]) << 24);
        *(unsigned int*)(wpk + (size_t)t * 65536 + o * C_IN + c4) = r;
    }
}

// ---------------------------------------------------------------------------
// Implicit GEMM, MX-scaled fp8 32x32x64 MFMA (unit scales => plain +/-1 dot).
// Same LDS staging + operand addresses as the verified R4/R5 32x32x16 path:
// chunk ks (channels c0+16*ks..+16) -> operand bytes [8*ks, 8*ks+8) at half hb.
// A and B use the identical (hb,byte)->channel placement, so any HW k-mapping
// yields the same sum; all scales 0x7F (=1.0) so scaling is a no-op.
__global__ __launch_bounds__(256, 2) void bconv_gemm(
    const unsigned char* __restrict__ apad,
    const unsigned char* __restrict__ wpk,
    const float* __restrict__ alpha,
    float* __restrict__ out)
{
    __shared__ __align__(16) unsigned char Al[AL_GRAN * 16];   // 17.2 KB
    __shared__ __align__(16) unsigned char Wl[WL_GRAN * 16];   // 24.6 KB

    const int tid = threadIdx.x;
    const int wv = tid >> 6, lane = tid & 63;
    const int l31 = lane & 31, hb = lane >> 5;

    const int bid = blockIdx.x;
    const int img = bid / 26;
    const int rem = bid - img * 26;
    const int tl = rem >> 1, ot = rem & 1;
    const int g0 = tl << 8;
    const int h0 = g0 / 56, w0 = g0 - h0 * 56;
    const int o_base = ot << 7;
    const int Q0 = (img * HP + h0) * WP + w0;

    int al_pos[5], al_sl[5];
#pragma unroll
    for (int it = 0; it < 5; ++it) {
        int s = (it < 4) ? (tid + (it << 8)) : (tid + 816);
        int pos = s >> 2, gI = s & 3;
        al_pos[it] = pos;
        al_sl[it]  = ((gI - (pos >> 1)) & 3) << 4;
    }
    int wl_off[6];
#pragma unroll
    for (int it = 0; it < 6; ++it) {
        int s = tid + (it << 8);
        int r = s >> 2, gI = s & 3;
        int kw = r >> 7, o = r & 127;
        int sl = (gI - (r >> 1)) & 3;
        wl_off[it] = kw * 65536 + o * 256 + (sl << 4);
    }

    const int o_half  = (wv >> 1) << 6;
    const int px_half = (wv & 1) << 7;

    int pos_tab[4], pxg[4];
#pragma unroll
    for (int nt = 0; nt < 4; ++nt) {
        int px = px_half + (nt << 5) + l31;
        pxg[nt] = g0 + px;
        int pxc = (pxg[nt] < GPI) ? px : (GPI - 1 - g0);
        pos_tab[nt] = pxc + 2 * ((w0 + pxc) / 56);
    }

    floatx16 acc[2][4] = {};

    for (int kh = 0; kh < 3; ++kh) {
        const int rowbase = Q0 + kh * WP;
        const int plim = (int)APAD_POS - 1 - rowbase;
        const unsigned char* asrc0 = apad + ((size_t)rowbase << 8);
        const unsigned char* wsrc0 = wpk + (size_t)(kh * 3) * 65536 + ((size_t)o_base << 8);
        for (int c0 = 0; c0 < C_IN; c0 += 64) {
            const unsigned char* asrc = asrc0 + c0;
            const unsigned char* wsrc = wsrc0 + c0;
            __syncthreads();
#pragma unroll
            for (int it = 0; it < 4; ++it) {
                int p = al_pos[it] < plim ? al_pos[it] : plim;
                glds16(asrc + ((size_t)p << 8) + al_sl[it],
                       &Al[(size_t)((it << 8) + (wv << 6)) << 4]);
            }
            {
                int p = al_pos[4] < plim ? al_pos[4] : plim;
                glds16(asrc + ((size_t)p << 8) + al_sl[4],
                       &Al[(size_t)(816 + (wv << 6)) << 4]);
            }
#pragma unroll
            for (int it = 0; it < 6; ++it)
                glds16(wsrc + wl_off[it],
                       &Wl[(size_t)((it << 8) + (wv << 6)) << 4]);
            __syncthreads();

#pragma unroll
            for (int kw = 0; kw < 3; ++kw) {
                union F { long l[4]; intx8 v; };
                F af[2];
#pragma unroll
                for (int mt = 0; mt < 2; ++mt) {
                    int r = (kw << 7) + o_half + (mt << 5) + l31;
#pragma unroll
                    for (int ks = 0; ks < 4; ++ks) {
                        int g = (r << 2) + ((ks + (r >> 1)) & 3);
                        af[mt].l[ks] = *(const long*)&Wl[(size_t)(g << 4) + (hb << 3)];
                    }
                }
#pragma unroll
                for (int nt = 0; nt < 4; ++nt) {
                    int pos = pos_tab[nt] + kw;
                    F bf;
#pragma unroll
                    for (int ks = 0; ks < 4; ++ks) {
                        int g = (pos << 2) + ((ks + (pos >> 1)) & 3);
                        bf.l[ks] = *(const long*)&Al[(size_t)(g << 4) + (hb << 3)];
                    }
#pragma unroll
                    for (int mt = 0; mt < 2; ++mt)
                        acc[mt][nt] = __builtin_amdgcn_mfma_scale_f32_32x32x64_f8f6f4(
                            af[mt].v, bf.v, acc[mt][nt],
                            0, 0,                      // cbsz=fp8(e4m3), blgp=fp8(e4m3)
                            0, 0x7F7F7F7F,             // opsel_a, scale_a = 1.0
                            0, 0x7F7F7F7F);            // opsel_b, scale_b = 1.0
                }
            }
        }
    }

#pragma unroll
    for (int mt = 0; mt < 2; ++mt) {
#pragma unroll
        for (int r = 0; r < 16; ++r) {
            int o_loc = o_half + (mt << 5) + (r & 3) + ((r >> 2) << 3) + (hb << 2);
            int o_g = o_base + o_loc;
            float a = alpha[o_g];
            float* ob = out + ((size_t)(img * O_OUT + o_g)) * GPI;
#pragma unroll
            for (int nt = 0; nt < 4; ++nt) {
                if (pxg[nt] < GPI) ob[pxg[nt]] = acc[mt][nt][r] * a;
            }
        }
    }
}

// ---------------------------------------------------------------------------
extern "C" void kernel_launch(void* const* d_in, const int* in_sizes, int n_in,
                              void* d_out, int out_size, void* d_ws, size_t ws_size,
                              hipStream_t stream) {
    const float* x     = (const float*)d_in[0];
    const float* M     = (const float*)d_in[1];
    const float* alpha = (const float*)d_in[2];
    float* out = (float*)d_out;

    unsigned char* apad = (unsigned char*)d_ws;
    unsigned char* wpk  = apad + APAD_BYTES;

    binarize_act<<<dim3(N_IMG * HP), dim3(256), 0, stream>>>(x, apad);
    pack_w<<<dim3(64), dim3(256), 0, stream>>>(M, wpk);
    bconv_gemm<<<dim3(N_IMG * TPI * 2), dim3(256), 0, stream>>>(apad, wpk, alpha, out);
}